// Round 2
// baseline (2994.102 us; speedup 1.0000x reference)
//
#include <hip/hip_runtime.h>
#include <hip/hip_bf16.h>
#include <hip/hip_fp16.h>

#define T_STEPS 512
#define BATCH   64
#define DIM     512            // INPUT_DIM == RNN_DIM
#define TOT_PAIRS 256          // DIM/2 half2 pairs
#define REG_PAIRS 192          // W_h pairs kept register-resident per thread

typedef _Float16 half2_t __attribute__((ext_vector_type(2)));
typedef short    bf16x8 __attribute__((ext_vector_type(8)));
typedef float    f32x4  __attribute__((ext_vector_type(4)));

static __device__ __forceinline__ unsigned short f2bf(float f) {
    union { float f; unsigned u; } v; v.f = f;
    unsigned r = v.u + 0x7fffu + ((v.u >> 16) & 1u);   // RNE
    return (unsigned short)(r >> 16);
}

// ------------- K1: transpose 512x512 fp32 region -> bf16 or fp16 -------------
__global__ __launch_bounds__(256) void tr_cvt_kernel(const float* __restrict__ src,
                                                     unsigned short* __restrict__ dst,
                                                     int to_fp16) {
    __shared__ float tile[32][33];
    const int bx = blockIdx.x * 32;   // dst row base (src col)
    const int by = blockIdx.y * 32;   // src row base
    const int tx = threadIdx.x;       // 32
    const int ty = threadIdx.y;       // 8
    #pragma unroll
    for (int i = ty; i < 32; i += 8)
        tile[i][tx] = src[(size_t)(by + i) * DIM + (bx + tx)];
    __syncthreads();
    #pragma unroll
    for (int i = ty; i < 32; i += 8) {
        float v = tile[tx][i];        // = src[by+tx][bx+i]
        unsigned short u;
        if (to_fp16) { __half hh = __float2half(v); u = __half_as_ushort(hh); }
        else         { u = f2bf(v); }
        dst[(size_t)(bx + i) * DIM + (by + tx)] = u;   // dst[n][k] = src[k][n]
    }
}

// ---------------- K2: Z = X @ Wx + bias  (bf16 MFMA, fp32 A loaded direct) ----------------
__global__ __launch_bounds__(256) void gemm_z_kernel(const float* __restrict__ X,            // [32768][512] f32
                                                     const unsigned short* __restrict__ WxT, // [512 n][512 k] bf16
                                                     const float* __restrict__ bias,         // [512]
                                                     _Float16* __restrict__ Zo) {            // [32768][512] f16
    const int bm   = blockIdx.x;            // 256 m-tiles of 128
    const int bn   = blockIdx.y;            // 4   n-tiles of 128
    const int wave = threadIdx.x >> 6;
    const int lane = threadIdx.x & 63;
    const int mBase = bm * 128 + (wave >> 1) * 64;
    const int nBase = bn * 128 + (wave & 1) * 64;
    const int l15 = lane & 15;
    const int q   = lane >> 4;
    f32x4 acc[4][4] = {};
    for (int kt = 0; kt < 512; kt += 32) {
        const int kk = kt + q * 8;
        bf16x8 a[4], b[4];
        #pragma unroll
        for (int i = 0; i < 4; ++i) {
            const float* ap = X + (size_t)(mBase + i * 16 + l15) * DIM + kk;
            float4 f0 = *(const float4*)(ap);
            float4 f1 = *(const float4*)(ap + 4);
            bf16x8 av;
            av[0] = (short)f2bf(f0.x); av[1] = (short)f2bf(f0.y);
            av[2] = (short)f2bf(f0.z); av[3] = (short)f2bf(f0.w);
            av[4] = (short)f2bf(f1.x); av[5] = (short)f2bf(f1.y);
            av[6] = (short)f2bf(f1.z); av[7] = (short)f2bf(f1.w);
            a[i] = av;
        }
        #pragma unroll
        for (int i = 0; i < 4; ++i)
            b[i] = *(const bf16x8*)(WxT + (size_t)(nBase + i * 16 + l15) * DIM + kk);
        #pragma unroll
        for (int mi = 0; mi < 4; ++mi)
            #pragma unroll
            for (int ni = 0; ni < 4; ++ni)
                acc[mi][ni] = __builtin_amdgcn_mfma_f32_16x16x32_bf16(a[mi], b[ni], acc[mi][ni], 0, 0, 0);
    }
    #pragma unroll
    for (int ni = 0; ni < 4; ++ni) {
        const int col = nBase + ni * 16 + l15;
        const float bv = bias[col];
        #pragma unroll
        for (int mi = 0; mi < 4; ++mi) {
            #pragma unroll
            for (int rg = 0; rg < 4; ++rg) {
                const int row = mBase + mi * 16 + q * 4 + rg;
                Zo[(size_t)row * DIM + col] = (_Float16)(acc[mi][ni][rg] + bv);
            }
        }
    }
}

// ---------------- K3: sequential recurrence, 1 WG per batch row ----------------
// thread j owns output column j. W_h column j: 192 pairs in VGPRs, 64 pairs streamed from L2.
// h exchanged via global double buffer (fp16). Strictly intra-WG communication.
__global__ __launch_bounds__(512, 2) void rnn_rec_kernel(const _Float16* __restrict__ Z,    // [T][B][512] f16
                                                         const half2_t* __restrict__ Wh,   // [512 j][256] fp16 pairs (=Wh^T)
                                                         const float* __restrict__ h0,     // [512]
                                                         float* __restrict__ out,          // [T][B][512]
                                                         half2_t* __restrict__ hbuf) {     // [2][B][256]
    const int r = blockIdx.x;
    const int j = threadIdx.x;
    const half2_t* wrow = Wh + (size_t)j * TOT_PAIRS;

    half2_t w[REG_PAIRS];
    #pragma unroll
    for (int p = 0; p < REG_PAIRS; ++p) w[p] = wrow[p];

    // emit h_0 = init_hidden (broadcast) and seed buffer 0
    float h = h0[j];
    out[(size_t)r * DIM + j] = h;
    ((_Float16*)(hbuf + (size_t)r * TOT_PAIRS))[j] = (_Float16)h;
    __syncthreads();

    for (int t = 0; t < T_STEPS - 1; ++t) {
        const half2_t* hp = hbuf + ((size_t)(t & 1) * BATCH + r) * TOT_PAIRS;
        float zv = (float)Z[((size_t)t * BATCH + r) * DIM + j];
        float a0 = zv, a1 = 0.f, a2 = 0.f, a3 = 0.f;
        #pragma unroll
        for (int p = 0; p < REG_PAIRS; p += 4) {
            half2_t h0v = hp[p + 0], h1v = hp[p + 1], h2v = hp[p + 2], h3v = hp[p + 3];
            a0 = __builtin_amdgcn_fdot2(w[p + 0], h0v, a0, false);
            a1 = __builtin_amdgcn_fdot2(w[p + 1], h1v, a1, false);
            a2 = __builtin_amdgcn_fdot2(w[p + 2], h2v, a2, false);
            a3 = __builtin_amdgcn_fdot2(w[p + 3], h3v, a3, false);
        }
        #pragma unroll
        for (int p = REG_PAIRS; p < TOT_PAIRS; p += 4) {
            half2_t w0 = wrow[p + 0], w1 = wrow[p + 1], w2 = wrow[p + 2], w3 = wrow[p + 3];
            half2_t h0v = hp[p + 0], h1v = hp[p + 1], h2v = hp[p + 2], h3v = hp[p + 3];
            a0 = __builtin_amdgcn_fdot2(w0, h0v, a0, false);
            a1 = __builtin_amdgcn_fdot2(w1, h1v, a1, false);
            a2 = __builtin_amdgcn_fdot2(w2, h2v, a2, false);
            a3 = __builtin_amdgcn_fdot2(w3, h3v, a3, false);
        }
        float hn = tanhf((a0 + a1) + (a2 + a3));
        out[((size_t)(t + 1) * BATCH + r) * DIM + j] = hn;
        ((_Float16*)(hbuf + ((size_t)((t + 1) & 1) * BATCH + r) * TOT_PAIRS))[j] = (_Float16)hn;
        __syncthreads();
    }
}

extern "C" void kernel_launch(void* const* d_in, const int* in_sizes, int n_in,
                              void* d_out, int out_size, void* d_ws, size_t ws_size,
                              hipStream_t stream) {
    const float* X    = (const float*)d_in[0];   // [512][64][512]
    const float* W    = (const float*)d_in[1];   // [1024][512]
    const float* bias = (const float*)d_in[2];   // [512]
    const float* h0   = (const float*)d_in[3];   // [512]
    float* out = (float*)d_out;

    char* ws = (char*)d_ws;
    unsigned short* WxT = (unsigned short*)(ws);                 //    524,288 B
    unsigned short* WhT = (unsigned short*)(ws + 524288);        //    524,288 B
    _Float16*       Zh  = (_Float16*)(ws + 1048576);             // 33,554,432 B
    half2_t*        hb  = (half2_t*)(ws + 34603008);             //    131,072 B
                                                                  // total 34,734,080 B

    dim3 tb(32, 8);
    tr_cvt_kernel<<<dim3(16, 16), tb, 0, stream>>>(W, WxT, 0);                 // Wx^T bf16
    tr_cvt_kernel<<<dim3(16, 16), tb, 0, stream>>>(W + 512 * 512, WhT, 1);     // Wh^T fp16
    gemm_z_kernel<<<dim3(256, 4), 256, 0, stream>>>(X, WxT, bias, Zh);
    rnn_rec_kernel<<<64, 512, 0, stream>>>(Zh, (const half2_t*)WhT, h0, out, hb);
}

// Round 4
// 1194.151 us; speedup vs baseline: 2.5073x; 2.5073x over previous
//
#include <hip/hip_runtime.h>
#include <hip/hip_bf16.h>
#include <hip/hip_fp16.h>

#define T_STEPS 512
#define BATCH   64
#define DIM     512            // INPUT_DIM == RNN_DIM
#define TOT_PAIRS 256          // DIM/2 half2 pairs
#define REG_PAIRS 160          // pairs [0,160): pinned in VGPRs
#define LDS_PAIRS 48           // pairs [160,208): staged in LDS
#define STR_PAIRS 48           // pairs [208,256): streamed from L2 each step

typedef _Float16 half2_t __attribute__((ext_vector_type(2)));
typedef _Float16 half8_t __attribute__((ext_vector_type(8)));
typedef short    bf16x8 __attribute__((ext_vector_type(8)));
typedef float    f32x4  __attribute__((ext_vector_type(4)));

static __device__ __forceinline__ unsigned short f2bf(float f) {
    union { float f; unsigned u; } v; v.f = f;
    unsigned r = v.u + 0x7fffu + ((v.u >> 16) & 1u);   // RNE
    return (unsigned short)(r >> 16);
}

static __device__ __forceinline__ float fast_tanh(float x) {
    // tanh(x) = 1 - 2/(exp(2x)+1); saturates correctly at +-inf
    float e = __expf(2.0f * x);
    return 1.0f - 2.0f * __builtin_amdgcn_rcpf(e + 1.0f);
}

// ------------- K1: transpose 512x512 fp32 region -> bf16 (for Wx^T) -------------
__global__ __launch_bounds__(256) void tr_cvt_kernel(const float* __restrict__ src,
                                                     unsigned short* __restrict__ dst) {
    __shared__ float tile[32][33];
    const int bx = blockIdx.x * 32;   // dst row base (src col)
    const int by = blockIdx.y * 32;   // src row base
    const int tx = threadIdx.x;       // 32
    const int ty = threadIdx.y;       // 8
    #pragma unroll
    for (int i = ty; i < 32; i += 8)
        tile[i][tx] = src[(size_t)(by + i) * DIM + (bx + tx)];
    __syncthreads();
    #pragma unroll
    for (int i = ty; i < 32; i += 8)
        dst[(size_t)(bx + i) * DIM + (by + tx)] = f2bf(tile[tx][i]);
}

// ------------- K1b: pack Wh pair-major fp16: WhP[p][j] = (W[512+2p][j], W[512+2p+1][j]) -------------
__global__ __launch_bounds__(256) void pack_wh_kernel(const float* __restrict__ W,
                                                      half2_t* __restrict__ WhP) {
    const int gid = blockIdx.x * 256 + threadIdx.x;   // p*512 + j
    const int p = gid >> 9, jj = gid & 511;
    float lo = W[(size_t)(512 + 2 * p) * DIM + jj];
    float hi = W[(size_t)(512 + 2 * p + 1) * DIM + jj];
    half2_t v; v[0] = (_Float16)lo; v[1] = (_Float16)hi;
    WhP[gid] = v;
}

// ---------------- K2: Z = X @ Wx + bias  (bf16 MFMA, fp32 A loaded direct) ----------------
__global__ __launch_bounds__(256) void gemm_z_kernel(const float* __restrict__ X,            // [32768][512] f32
                                                     const unsigned short* __restrict__ WxT, // [512 n][512 k] bf16
                                                     const float* __restrict__ bias,         // [512]
                                                     _Float16* __restrict__ Zo) {            // [32768][512] f16
    const int bm   = blockIdx.y;            // 256 m-tiles of 128
    const int bn   = blockIdx.x;            // 4   n-tiles of 128 (fastest -> share X m-tile in L2)
    const int wave = threadIdx.x >> 6;
    const int lane = threadIdx.x & 63;
    const int mBase = bm * 128 + (wave >> 1) * 64;
    const int nBase = bn * 128 + (wave & 1) * 64;
    const int l15 = lane & 15;
    const int q   = lane >> 4;
    f32x4 acc[4][4] = {};
    for (int kt = 0; kt < 512; kt += 32) {
        const int kk = kt + q * 8;
        bf16x8 a[4], b[4];
        #pragma unroll
        for (int i = 0; i < 4; ++i) {
            const float* ap = X + (size_t)(mBase + i * 16 + l15) * DIM + kk;
            float4 f0 = *(const float4*)(ap);
            float4 f1 = *(const float4*)(ap + 4);
            bf16x8 av;
            av[0] = (short)f2bf(f0.x); av[1] = (short)f2bf(f0.y);
            av[2] = (short)f2bf(f0.z); av[3] = (short)f2bf(f0.w);
            av[4] = (short)f2bf(f1.x); av[5] = (short)f2bf(f1.y);
            av[6] = (short)f2bf(f1.z); av[7] = (short)f2bf(f1.w);
            a[i] = av;
        }
        #pragma unroll
        for (int i = 0; i < 4; ++i)
            b[i] = *(const bf16x8*)(WxT + (size_t)(nBase + i * 16 + l15) * DIM + kk);
        #pragma unroll
        for (int mi = 0; mi < 4; ++mi)
            #pragma unroll
            for (int ni = 0; ni < 4; ++ni)
                acc[mi][ni] = __builtin_amdgcn_mfma_f32_16x16x32_bf16(a[mi], b[ni], acc[mi][ni], 0, 0, 0);
    }
    #pragma unroll
    for (int ni = 0; ni < 4; ++ni) {
        const int col = nBase + ni * 16 + l15;
        const float bv = bias[col];
        #pragma unroll
        for (int mi = 0; mi < 4; ++mi) {
            #pragma unroll
            for (int rg = 0; rg < 4; ++rg) {
                const int row = mBase + mi * 16 + q * 4 + rg;
                Zo[(size_t)row * DIM + col] = (_Float16)(acc[mi][ni][rg] + bv);
            }
        }
    }
}

// ---------------- K3: sequential recurrence, 1 WG per batch row (each WG owns a CU) ----------------
// thread j owns column j. W col j: 160 pairs pinned in VGPRs, 48 in LDS, 48 streamed (coalesced).
// h double-buffered in LDS (broadcast b128 reads); barrier drains LDS only.
__global__ __launch_bounds__(512, 2) void rnn_rec_kernel(const _Float16* __restrict__ Z,    // [T][B][512] f16
                                                         const half2_t* __restrict__ WhP,  // [256 p][512 j]
                                                         const float* __restrict__ h0,     // [512]
                                                         float* __restrict__ out) {        // [T][B][512]
    __shared__ float wlds_raw[LDS_PAIRS * DIM];       // [p'][col], half2 payload in 4B
    __shared__ _Float16 hsh[2][DIM];
    const int r = blockIdx.x;
    const int j = threadIdx.x;

    // stage LDS portion of W (coalesced read, contiguous write)
    {
        const float* src = (const float*)(WhP + (size_t)REG_PAIRS * DIM);
        #pragma unroll
        for (int k = 0; k < LDS_PAIRS; ++k)
            wlds_raw[k * DIM + j] = src[k * DIM + j];
    }
    // register-resident W, pinned so the compiler cannot sink the loads into the t-loop
    half2_t w[REG_PAIRS];
    #pragma unroll
    for (int p = 0; p < REG_PAIRS; ++p) w[p] = WhP[(size_t)p * DIM + j];
    #pragma unroll
    for (int p = 0; p < REG_PAIRS; ++p) asm volatile("" : "+v"(w[p]));

    float h = h0[j];
    out[(size_t)r * DIM + j] = h;
    hsh[0][j] = (_Float16)h;
    __syncthreads();

    const half2_t* wl = (const half2_t*)wlds_raw;
    float zv = (float)Z[(size_t)r * DIM + j];

    for (int t = 0; t < T_STEPS - 1; ++t) {
        // prefetch next-step z (independent of h)
        float zn = (float)Z[((size_t)(t + 1) * BATCH + r) * DIM + j];
        // issue all streamed-W loads up front; consumed at loop tail (latency hidden)
        half2_t sw[STR_PAIRS];
        #pragma unroll
        for (int p = 0; p < STR_PAIRS; ++p)
            sw[p] = WhP[(size_t)(REG_PAIRS + LDS_PAIRS + p) * DIM + j];

        const half8_t* h8 = (const half8_t*)&hsh[t & 1][0];
        float a0 = zv, a1 = 0.f, a2 = 0.f, a3 = 0.f;
        #pragma unroll
        for (int c = 0; c < REG_PAIRS / 4; ++c) {          // 40 chunks
            half8_t hv = h8[c];
            a0 = __builtin_amdgcn_fdot2(w[4*c+0], __builtin_shufflevector(hv, hv, 0, 1), a0, false);
            a1 = __builtin_amdgcn_fdot2(w[4*c+1], __builtin_shufflevector(hv, hv, 2, 3), a1, false);
            a2 = __builtin_amdgcn_fdot2(w[4*c+2], __builtin_shufflevector(hv, hv, 4, 5), a2, false);
            a3 = __builtin_amdgcn_fdot2(w[4*c+3], __builtin_shufflevector(hv, hv, 6, 7), a3, false);
        }
        #pragma unroll
        for (int c = 0; c < LDS_PAIRS / 4; ++c) {          // 12 chunks
            half8_t hv = h8[REG_PAIRS / 4 + c];
            a0 = __builtin_amdgcn_fdot2(wl[(4*c+0) * DIM + j], __builtin_shufflevector(hv, hv, 0, 1), a0, false);
            a1 = __builtin_amdgcn_fdot2(wl[(4*c+1) * DIM + j], __builtin_shufflevector(hv, hv, 2, 3), a1, false);
            a2 = __builtin_amdgcn_fdot2(wl[(4*c+2) * DIM + j], __builtin_shufflevector(hv, hv, 4, 5), a2, false);
            a3 = __builtin_amdgcn_fdot2(wl[(4*c+3) * DIM + j], __builtin_shufflevector(hv, hv, 6, 7), a3, false);
        }
        #pragma unroll
        for (int c = 0; c < STR_PAIRS / 4; ++c) {          // 12 chunks
            half8_t hv = h8[(REG_PAIRS + LDS_PAIRS) / 4 + c];
            a0 = __builtin_amdgcn_fdot2(sw[4*c+0], __builtin_shufflevector(hv, hv, 0, 1), a0, false);
            a1 = __builtin_amdgcn_fdot2(sw[4*c+1], __builtin_shufflevector(hv, hv, 2, 3), a1, false);
            a2 = __builtin_amdgcn_fdot2(sw[4*c+2], __builtin_shufflevector(hv, hv, 4, 5), a2, false);
            a3 = __builtin_amdgcn_fdot2(sw[4*c+3], __builtin_shufflevector(hv, hv, 6, 7), a3, false);
        }
        float hn = fast_tanh((a0 + a1) + (a2 + a3));
        out[((size_t)(t + 1) * BATCH + r) * DIM + j] = hn;
        hsh[(t + 1) & 1][j] = (_Float16)hn;
        zv = zn;
        // LDS-only drain + barrier: out-stores / z-prefetch / W-stream keep flying
        asm volatile("s_waitcnt lgkmcnt(0)\n\ts_barrier" ::: "memory");
    }
}

extern "C" void kernel_launch(void* const* d_in, const int* in_sizes, int n_in,
                              void* d_out, int out_size, void* d_ws, size_t ws_size,
                              hipStream_t stream) {
    const float* X    = (const float*)d_in[0];   // [512][64][512]
    const float* W    = (const float*)d_in[1];   // [1024][512]
    const float* bias = (const float*)d_in[2];   // [512]
    const float* h0   = (const float*)d_in[3];   // [512]
    float* out = (float*)d_out;

    char* ws = (char*)d_ws;
    unsigned short* WxT = (unsigned short*)(ws);                 //    524,288 B
    half2_t*        WhP = (half2_t*)(ws + 524288);               //    524,288 B
    _Float16*       Zh  = (_Float16*)(ws + 1048576);             // 33,554,432 B
                                                                  // total 34,603,008 B

    dim3 tb(32, 8);
    tr_cvt_kernel<<<dim3(16, 16), tb, 0, stream>>>(W, WxT);            // Wx^T bf16
    pack_wh_kernel<<<512, 256, 0, stream>>>(W, WhP);                   // Wh pair-major fp16
    gemm_z_kernel<<<dim3(4, 256), 256, 0, stream>>>(X, WxT, bias, Zh);
    rnn_rec_kernel<<<64, 512, 0, stream>>>(Zh, WhP, h0, out);
}

// Round 5
// 1115.892 us; speedup vs baseline: 2.6831x; 1.0701x over previous
//
#include <hip/hip_runtime.h>
#include <hip/hip_bf16.h>
#include <hip/hip_fp16.h>

#define T_STEPS 512
#define BATCH   64
#define DIM     512            // INPUT_DIM == RNN_DIM
#define TOT_PAIRS 256          // DIM/2 half2 pairs
#define REG_PAIRS 160          // pairs [0,160): pinned in VGPRs
#define LDS_PAIRS 64           // pairs [160,224): staged in LDS (packed 4-pair b128)
#define STR_PAIRS 32           // pairs [224,256): streamed from L2 each step (2 chunks of 16)

typedef _Float16 half2_t __attribute__((ext_vector_type(2)));
typedef _Float16 half8_t __attribute__((ext_vector_type(8)));
typedef short    bf16x8 __attribute__((ext_vector_type(8)));
typedef float    f32x4  __attribute__((ext_vector_type(4)));

static __device__ __forceinline__ unsigned short f2bf(float f) {
    union { float f; unsigned u; } v; v.f = f;
    unsigned r = v.u + 0x7fffu + ((v.u >> 16) & 1u);   // RNE
    return (unsigned short)(r >> 16);
}

static __device__ __forceinline__ float fast_tanh(float x) {
    float e = __expf(2.0f * x);
    return 1.0f - 2.0f * __builtin_amdgcn_rcpf(e + 1.0f);
}

// ------------- K1: transpose 512x512 fp32 region -> bf16 (for Wx^T) -------------
__global__ __launch_bounds__(256) void tr_cvt_kernel(const float* __restrict__ src,
                                                     unsigned short* __restrict__ dst) {
    __shared__ float tile[32][33];
    const int bx = blockIdx.x * 32;
    const int by = blockIdx.y * 32;
    const int tx = threadIdx.x;       // 32
    const int ty = threadIdx.y;       // 8
    #pragma unroll
    for (int i = ty; i < 32; i += 8)
        tile[i][tx] = src[(size_t)(by + i) * DIM + (bx + tx)];
    __syncthreads();
    #pragma unroll
    for (int i = ty; i < 32; i += 8)
        dst[(size_t)(bx + i) * DIM + (by + tx)] = f2bf(tile[tx][i]);
}

// ------------- K1b: pack Wh pair-major fp16: WhP[p][j] = (W[512+2p][j], W[512+2p+1][j]) -------------
__global__ __launch_bounds__(256) void pack_wh_kernel(const float* __restrict__ W,
                                                      half2_t* __restrict__ WhP) {
    const int gid = blockIdx.x * 256 + threadIdx.x;   // p*512 + j
    const int p = gid >> 9, jj = gid & 511;
    float lo = W[(size_t)(512 + 2 * p) * DIM + jj];
    float hi = W[(size_t)(512 + 2 * p + 1) * DIM + jj];
    half2_t v; v[0] = (_Float16)lo; v[1] = (_Float16)hi;
    WhP[gid] = v;
}

// ---------------- K2: Z = X @ Wx + bias  (bf16 MFMA, fp32 A loaded direct) ----------------
__global__ __launch_bounds__(256) void gemm_z_kernel(const float* __restrict__ X,            // [32768][512] f32
                                                     const unsigned short* __restrict__ WxT, // [512 n][512 k] bf16
                                                     const float* __restrict__ bias,         // [512]
                                                     _Float16* __restrict__ Zo) {            // [32768][512] f16
    const int bm   = blockIdx.y;
    const int bn   = blockIdx.x;
    const int wave = threadIdx.x >> 6;
    const int lane = threadIdx.x & 63;
    const int mBase = bm * 128 + (wave >> 1) * 64;
    const int nBase = bn * 128 + (wave & 1) * 64;
    const int l15 = lane & 15;
    const int q   = lane >> 4;
    f32x4 acc[4][4] = {};
    for (int kt = 0; kt < 512; kt += 32) {
        const int kk = kt + q * 8;
        bf16x8 a[4], b[4];
        #pragma unroll
        for (int i = 0; i < 4; ++i) {
            const float* ap = X + (size_t)(mBase + i * 16 + l15) * DIM + kk;
            float4 f0 = *(const float4*)(ap);
            float4 f1 = *(const float4*)(ap + 4);
            bf16x8 av;
            av[0] = (short)f2bf(f0.x); av[1] = (short)f2bf(f0.y);
            av[2] = (short)f2bf(f0.z); av[3] = (short)f2bf(f0.w);
            av[4] = (short)f2bf(f1.x); av[5] = (short)f2bf(f1.y);
            av[6] = (short)f2bf(f1.z); av[7] = (short)f2bf(f1.w);
            a[i] = av;
        }
        #pragma unroll
        for (int i = 0; i < 4; ++i)
            b[i] = *(const bf16x8*)(WxT + (size_t)(nBase + i * 16 + l15) * DIM + kk);
        #pragma unroll
        for (int mi = 0; mi < 4; ++mi)
            #pragma unroll
            for (int ni = 0; ni < 4; ++ni)
                acc[mi][ni] = __builtin_amdgcn_mfma_f32_16x16x32_bf16(a[mi], b[ni], acc[mi][ni], 0, 0, 0);
    }
    #pragma unroll
    for (int ni = 0; ni < 4; ++ni) {
        const int col = nBase + ni * 16 + l15;
        const float bv = bias[col];
        #pragma unroll
        for (int mi = 0; mi < 4; ++mi) {
            #pragma unroll
            for (int rg = 0; rg < 4; ++rg) {
                const int row = mBase + mi * 16 + q * 4 + rg;
                Zo[(size_t)row * DIM + col] = (_Float16)(acc[mi][ni][rg] + bv);
            }
        }
    }
}

// ---------------- K3: sequential recurrence, 1 WG per batch row (CU-exclusive) ----------------
// thread j owns column j. W col j: 160 pairs pinned in VGPRs, 64 in LDS (b128-packed),
// 32 streamed from L2 in 2 chunks of 16. h double-buffered in LDS; barrier drains LDS only.
__global__ __launch_bounds__(512, 2) void rnn_rec_kernel(const _Float16* __restrict__ Z,    // [T][B][512] f16
                                                         const half2_t* __restrict__ WhP,  // [256 p][512 j]
                                                         const float* __restrict__ h0,     // [512]
                                                         float* __restrict__ out) {        // [T][B][512]
    __shared__ half8_t wlds4[(LDS_PAIRS / 4) * DIM];  // [g][j]: pairs 160+4g..160+4g+3 of col j (128 KB)
    __shared__ _Float16 hsh[2][DIM];                  // 2 KB
    const int r = blockIdx.x;
    const int j = threadIdx.x;

    // stage LDS W slice: 4 coalesced b32 global reads -> one b128 LDS write per group
    #pragma unroll
    for (int g = 0; g < LDS_PAIRS / 4; ++g) {
        half2_t p0 = WhP[(size_t)(REG_PAIRS + 4 * g + 0) * DIM + j];
        half2_t p1 = WhP[(size_t)(REG_PAIRS + 4 * g + 1) * DIM + j];
        half2_t p2 = WhP[(size_t)(REG_PAIRS + 4 * g + 2) * DIM + j];
        half2_t p3 = WhP[(size_t)(REG_PAIRS + 4 * g + 3) * DIM + j];
        half8_t v;
        v[0] = p0[0]; v[1] = p0[1]; v[2] = p1[0]; v[3] = p1[1];
        v[4] = p2[0]; v[5] = p2[1]; v[6] = p3[0]; v[7] = p3[1];
        wlds4[g * DIM + j] = v;
    }
    // register-resident W, pinned (opaque to the allocator -> cannot rematerialize)
    half2_t w[REG_PAIRS];
    #pragma unroll
    for (int p = 0; p < REG_PAIRS; ++p) w[p] = WhP[(size_t)p * DIM + j];
    #pragma unroll
    for (int p = 0; p < REG_PAIRS; ++p) asm volatile("" : "+v"(w[p]));

    float h = h0[j];
    out[(size_t)r * DIM + j] = h;
    hsh[0][j] = (_Float16)h;
    __syncthreads();

    float zv = (float)Z[(size_t)r * DIM + j];

    for (int t = 0; t < T_STEPS - 1; ++t) {
        // prefetch next-step z (independent of h)
        float zn = (float)Z[((size_t)(t + 1) * BATCH + r) * DIM + j];
        // stream chunk 0 (pairs 224..239) issued now, consumed at tail
        half2_t sw0[16];
        #pragma unroll
        for (int p = 0; p < 16; ++p)
            sw0[p] = WhP[(size_t)(REG_PAIRS + LDS_PAIRS + p) * DIM + j];

        const half8_t* h8 = (const half8_t*)&hsh[t & 1][0];
        float a0 = zv, a1 = 0.f, a2 = 0.f, a3 = 0.f;
        #pragma unroll
        for (int c = 0; c < REG_PAIRS / 4; ++c) {          // 40 chunks, register W
            half8_t hv = h8[c];
            a0 = __builtin_amdgcn_fdot2(w[4*c+0], __builtin_shufflevector(hv, hv, 0, 1), a0, false);
            a1 = __builtin_amdgcn_fdot2(w[4*c+1], __builtin_shufflevector(hv, hv, 2, 3), a1, false);
            a2 = __builtin_amdgcn_fdot2(w[4*c+2], __builtin_shufflevector(hv, hv, 4, 5), a2, false);
            a3 = __builtin_amdgcn_fdot2(w[4*c+3], __builtin_shufflevector(hv, hv, 6, 7), a3, false);
        }
        // stream chunk 1 (pairs 240..255)
        half2_t sw1[16];
        #pragma unroll
        for (int p = 0; p < 16; ++p)
            sw1[p] = WhP[(size_t)(REG_PAIRS + LDS_PAIRS + 16 + p) * DIM + j];
        #pragma unroll
        for (int g = 0; g < LDS_PAIRS / 4; ++g) {          // 16 chunks, LDS W (b128)
            half8_t hv = h8[REG_PAIRS / 4 + g];
            half8_t wv = wlds4[g * DIM + j];
            a0 = __builtin_amdgcn_fdot2(__builtin_shufflevector(wv, wv, 0, 1), __builtin_shufflevector(hv, hv, 0, 1), a0, false);
            a1 = __builtin_amdgcn_fdot2(__builtin_shufflevector(wv, wv, 2, 3), __builtin_shufflevector(hv, hv, 2, 3), a1, false);
            a2 = __builtin_amdgcn_fdot2(__builtin_shufflevector(wv, wv, 4, 5), __builtin_shufflevector(hv, hv, 4, 5), a2, false);
            a3 = __builtin_amdgcn_fdot2(__builtin_shufflevector(wv, wv, 6, 7), __builtin_shufflevector(hv, hv, 6, 7), a3, false);
        }
        #pragma unroll
        for (int c = 0; c < 4; ++c) {                      // stream chunk 0 consume
            half8_t hv = h8[(REG_PAIRS + LDS_PAIRS) / 4 + c];
            a0 = __builtin_amdgcn_fdot2(sw0[4*c+0], __builtin_shufflevector(hv, hv, 0, 1), a0, false);
            a1 = __builtin_amdgcn_fdot2(sw0[4*c+1], __builtin_shufflevector(hv, hv, 2, 3), a1, false);
            a2 = __builtin_amdgcn_fdot2(sw0[4*c+2], __builtin_shufflevector(hv, hv, 4, 5), a2, false);
            a3 = __builtin_amdgcn_fdot2(sw0[4*c+3], __builtin_shufflevector(hv, hv, 6, 7), a3, false);
        }
        #pragma unroll
        for (int c = 0; c < 4; ++c) {                      // stream chunk 1 consume
            half8_t hv = h8[(REG_PAIRS + LDS_PAIRS) / 4 + 4 + c];
            a0 = __builtin_amdgcn_fdot2(sw1[4*c+0], __builtin_shufflevector(hv, hv, 0, 1), a0, false);
            a1 = __builtin_amdgcn_fdot2(sw1[4*c+1], __builtin_shufflevector(hv, hv, 2, 3), a1, false);
            a2 = __builtin_amdgcn_fdot2(sw1[4*c+2], __builtin_shufflevector(hv, hv, 4, 5), a2, false);
            a3 = __builtin_amdgcn_fdot2(sw1[4*c+3], __builtin_shufflevector(hv, hv, 6, 7), a3, false);
        }
        float hn = fast_tanh((a0 + a1) + (a2 + a3));
        out[((size_t)(t + 1) * BATCH + r) * DIM + j] = hn;
        hsh[(t + 1) & 1][j] = (_Float16)hn;
        zv = zn;
        // LDS-only drain + barrier: out-stores / z-prefetch / W-stream stay in flight
        asm volatile("s_waitcnt lgkmcnt(0)\n\ts_barrier" ::: "memory");
    }
}

extern "C" void kernel_launch(void* const* d_in, const int* in_sizes, int n_in,
                              void* d_out, int out_size, void* d_ws, size_t ws_size,
                              hipStream_t stream) {
    const float* X    = (const float*)d_in[0];   // [512][64][512]
    const float* W    = (const float*)d_in[1];   // [1024][512]
    const float* bias = (const float*)d_in[2];   // [512]
    const float* h0   = (const float*)d_in[3];   // [512]
    float* out = (float*)d_out;

    char* ws = (char*)d_ws;
    unsigned short* WxT = (unsigned short*)(ws);                 //    524,288 B
    half2_t*        WhP = (half2_t*)(ws + 524288);               //    524,288 B
    _Float16*       Zh  = (_Float16*)(ws + 1048576);             // 33,554,432 B
                                                                  // total 34,603,008 B

    dim3 tb(32, 8);
    tr_cvt_kernel<<<dim3(16, 16), tb, 0, stream>>>(W, WxT);            // Wx^T bf16
    pack_wh_kernel<<<512, 256, 0, stream>>>(W, WhP);                   // Wh pair-major fp16
    gemm_z_kernel<<<dim3(4, 256), 256, 0, stream>>>(X, WxT, bias, Zh);
    rnn_rec_kernel<<<64, 512, 0, stream>>>(Zh, WhP, h0, out);
}